// Round 5
// baseline (647.685 us; speedup 1.0000x reference)
//
#include <hip/hip_runtime.h>

// ---------------- problem constants ----------------
#define N_NODES 30000
#define N_EDGES 480000
#define E_TOT   510000        // edges + self loops
#define BQ      4096
#define IN_DIM  1281
#define KP1     1312          // 1281 padded to mult of 32
#define MP      30080         // 30000 padded to mult of 128
#define NBM     235           // MP/128
#define TS1     (KP1*128)     // A'/B' tile stride (shorts), layer 1
#define TS2     (256*128)     // tile stride, layer 2

typedef __attribute__((ext_vector_type(8))) short bf16x8;
typedef __attribute__((ext_vector_type(4))) float f32x4;

__device__ __forceinline__ short f2bf(float f) {
    unsigned int u = __builtin_bit_cast(unsigned int, f);
    u += 0x7fffu + ((u >> 16) & 1u);       // RNE
    return (short)(u >> 16);
}

__device__ __forceinline__ float bf2f(short s) {
    unsigned int u = ((unsigned int)(unsigned short)s) << 16;
    return __builtin_bit_cast(float, u);
}

__device__ __forceinline__ void async16(void* lds, const void* g) {
    __builtin_amdgcn_global_load_lds(
        (const __attribute__((address_space(1))) void*)g,
        (__attribute__((address_space(3))) void*)lds, 16, 0, 0);
}

__device__ __forceinline__ float elu1(float x) {
    return x > 0.f ? x : __expf(x) - 1.f;
}

__device__ __forceinline__ float lrelu(float x) {
    return x > 0.f ? x : 0.2f * x;
}

// ---------------- pack kernels ----------------
// x (30000x1281 f32) -> A' tile-major: A'[mt][kchunk][m&127][k&7] bf16.
// Block (mt, g) handles 8 rows m0=mt*128+g*8. LDS row stride 1320 shorts.
// Pad rows (>=30000) are never written: they only feed dead C rows, and the
// 0xAA poison there is a finite bf16 (no NaN). Pad COLS are zeroed via B'.
__global__ __launch_bounds__(256) void pack_x_kernel(const float* __restrict__ x,
                                                     short* __restrict__ A) {
    __shared__ short L[8 * 1320];
    const int mt = blockIdx.x, g = blockIdx.y;
    const int t = threadIdx.x;
    const int m0 = mt * 128 + g * 8;
    if (m0 >= N_NODES) return;
    #pragma unroll
    for (int r = 0; r < 8; ++r) {
        const float* src = x + (size_t)(m0 + r) * IN_DIM;
        for (int c = t; c < IN_DIM; c += 256) L[r * 1320 + c] = f2bf(src[c]);
        if (t < KP1 - IN_DIM) L[r * 1320 + IN_DIM + t] = 0;  // zero col pad (LDS garbage could be NaN)
    }
    __syncthreads();
    short* Atile = A + (size_t)mt * TS1;
    for (int u = t; u < (KP1 / 8) * 8; u += 256) {
        int tc = u >> 3, r = u & 7;
        *(bf16x8*)(Atile + (size_t)tc * 1024 + (size_t)(g * 8 + r) * 8) =
            *(const bf16x8*)&L[r * 1320 + tc * 8];
    }
}

// W (K x 256 row-major, Wl|Wr) -> B'[bt][kchunk][n&127][k&7]; k-pad zeroed.
// Block (kc, bt): 8 k-rows x 128 n-cols.
__global__ __launch_bounds__(256) void pack_w_kernel(const float* __restrict__ Wl,
                                                     const float* __restrict__ Wr,
                                                     short* __restrict__ Bt,
                                                     int K, int Kp) {
    __shared__ short L[8][128];
    const int kc = blockIdx.x, bt = blockIdx.y;
    const int t = threadIdx.x;
    const float* W = (bt < 2) ? Wl : Wr;
    const int ncol0 = (bt & 1) * 128;
    #pragma unroll
    for (int pass = 0; pass < 4; ++pass) {
        int u = pass * 256 + t;               // 1024 elems: k_r = u>>7, n_l = u&127
        int k_r = u >> 7, n_l = u & 127;
        int k = kc * 8 + k_r;
        L[k_r][n_l] = (k < K) ? f2bf(W[(size_t)k * 256 + ncol0 + n_l]) : (short)0;
    }
    __syncthreads();
    if (t < 128) {
        bf16x8 v;
        #pragma unroll
        for (int j = 0; j < 8; ++j) v[j] = L[j][t];
        *(bf16x8*)(Bt + (size_t)bt * ((size_t)Kp * 128) + (size_t)kc * 1024 + (size_t)t * 8) = v;
    }
}

// ---------------- bf16 MFMA GEMM, 128x128 tile, tiled layouts ----------------
// C(M x 512 bf16) = A'(tiles) * B'(tiles)^T + bias.
// Staging: per K-iter one contiguous 8-KB slab per matrix (perfect sequential
// streams). XCD swizzle: 4 blocks sharing an A-tile get ids == same mod 8
// (same XCD round-robin slot) within one 32-id group -> A hits that XCD's L2.
__global__ __launch_bounds__(256) void gemm_bf16_kernel(
    const short* __restrict__ A, const short* __restrict__ B,
    short* __restrict__ C,
    const float* __restrict__ biasLo, const float* __restrict__ biasHi,
    int Mstore, int Kp)
{
    __shared__ short As[4096];   // [4 kc][128 m][8 k]
    __shared__ short Bs[4096];
    const int id = blockIdx.x;
    int bmT, bnT;
    if (id < 928) { int grp = id >> 5, w32 = id & 31; bmT = grp * 8 + (w32 & 7); bnT = w32 >> 3; }
    else          { int r = id - 928;  bmT = 232 + (r >> 2); bnT = r & 3; }
    const int tid  = threadIdx.x;
    const int wave = tid >> 6;
    const int lane = tid & 63;
    const int l15  = lane & 15;
    const int quad = lane >> 4;

    const size_t tstride = (size_t)Kp * 128;
    const short* aPtr = A + (size_t)bmT * tstride + wave * 1024 + lane * 8;
    const short* bPtr = B + (size_t)bnT * tstride + wave * 1024 + lane * 8;
    short* AsW = &As[wave * 1024];
    short* BsW = &Bs[wave * 1024];

    const int wm = (wave & 1) * 64;
    const int wn = (wave >> 1) * 64;

    f32x4 acc[4][4] = {};

    for (int it = 0; it < Kp / 32; ++it) {
        async16(AsW,       aPtr);
        async16(AsW + 512, aPtr + 512);
        async16(BsW,       bPtr);
        async16(BsW + 512, bPtr + 512);
        aPtr += 4096; bPtr += 4096;
        __syncthreads();

        bf16x8 af[4], bfr[4];
        #pragma unroll
        for (int i = 0; i < 4; ++i)
            af[i] = *(const bf16x8*)&As[quad * 1024 + (wm + i * 16 + l15) * 8];
        #pragma unroll
        for (int i = 0; i < 4; ++i)
            bfr[i] = *(const bf16x8*)&Bs[quad * 1024 + (wn + i * 16 + l15) * 8];
        #pragma unroll
        for (int mi = 0; mi < 4; ++mi)
            #pragma unroll
            for (int ni = 0; ni < 4; ++ni)
                acc[mi][ni] = __builtin_amdgcn_mfma_f32_16x16x32_bf16(
                    af[mi], bfr[ni], acc[mi][ni], 0, 0, 0);
        __syncthreads();
    }

    // C/D layout: col = lane&15, row = quad*4 + reg  [measured m89/m91]
    const int bm = bmT * 128, bn = bnT * 128;
    #pragma unroll
    for (int mi = 0; mi < 4; ++mi) {
        int row = bm + wm + mi * 16 + quad * 4;
        #pragma unroll
        for (int ni = 0; ni < 4; ++ni) {
            int col = bn + wn + ni * 16 + l15;
            float bv = (col < 256) ? biasLo[col] : biasHi[col - 256];
            #pragma unroll
            for (int r = 0; r < 4; ++r) {
                int rr = row + r;
                if (rr < Mstore)
                    C[(size_t)rr * 512 + col] = f2bf(acc[mi][ni][r] + bv);
            }
        }
    }
}

// ---------------- CSR build (grouped by dst) ----------------
__global__ __launch_bounds__(256) void edge_count_kernel(const int* __restrict__ ei,
                                                         int* __restrict__ counts) {
    int e = blockIdx.x * 256 + threadIdx.x;
    if (e >= E_TOT) return;
    int dst = (e < N_EDGES) ? ei[N_EDGES + e] : (e - N_EDGES);
    atomicAdd(&counts[dst], 1);
}

// single block, 1024 threads x 32 nodes each; one barrier phase
__global__ __launch_bounds__(1024) void scan_kernel(const int* __restrict__ counts,
                                                    int* __restrict__ offs,
                                                    int* __restrict__ cursor) {
    __shared__ int wsum[16];
    int t = threadIdx.x;
    int lane = t & 63, wv = t >> 6;
    int base = t * 32;
    int local[32];
    int s = 0;
    #pragma unroll
    for (int j = 0; j < 32; ++j) {
        int i = base + j;
        int c = (i < N_NODES) ? counts[i] : 0;
        local[j] = s;
        s += c;
    }
    int incl = s;
    #pragma unroll
    for (int off = 1; off < 64; off <<= 1) {
        int v = __shfl_up(incl, off, 64);
        if (lane >= off) incl += v;
    }
    if (lane == 63) wsum[wv] = incl;
    __syncthreads();
    if (t == 0) {
        int run = 0;
        #pragma unroll
        for (int w2 = 0; w2 < 16; ++w2) { int v = wsum[w2]; wsum[w2] = run; run += v; }
        offs[N_NODES] = run;
    }
    __syncthreads();
    int thrExc = wsum[wv] + incl - s;
    #pragma unroll
    for (int j = 0; j < 32; ++j) {
        int i = base + j;
        if (i < N_NODES) {
            int o = thrExc + local[j];
            offs[i] = o;
            cursor[i] = o;
        }
    }
}

__global__ __launch_bounds__(256) void edge_scatter_kernel(const int* __restrict__ ei,
                                                           int* __restrict__ cursor,
                                                           int* __restrict__ srcs) {
    int e = blockIdx.x * 256 + threadIdx.x;
    if (e >= E_TOT) return;
    int src, dst;
    if (e < N_EDGES) { src = ei[e]; dst = ei[N_EDGES + e]; }
    else { src = e - N_EDGES; dst = src; }
    int pos = atomicAdd(&cursor[dst], 1);
    srcs[pos] = src;
}

// ---------------- layer-1 fused logits+softmax+aggregate ----------------
// one wave per dst node, two edges per iteration (half-waves); lane owns 8 dims.
// Output written directly in A'-tile layout for GEMM2.
__global__ __launch_bounds__(256) void fused_aggr1_kernel(
    const int* __restrict__ offs, const int* __restrict__ srcs,
    const short* __restrict__ C, const float* __restrict__ att,
    const float* __restrict__ bias, short* __restrict__ h1b)
{
    int wid = (int)((blockIdx.x * 256 + threadIdx.x) >> 6);
    int lane = threadIdx.x & 63;
    if (wid >= N_NODES) return;
    int n = wid;
    int half = lane >> 5;
    int l5 = lane & 31;
    int d0 = l5 * 8;
    float attv[8], xr[8];
    {
        float4 aa = *(const float4*)(att + d0);
        float4 ab = *(const float4*)(att + d0 + 4);
        attv[0]=aa.x; attv[1]=aa.y; attv[2]=aa.z; attv[3]=aa.w;
        attv[4]=ab.x; attv[5]=ab.y; attv[6]=ab.z; attv[7]=ab.w;
        bf16x8 xv = *(const bf16x8*)(C + (size_t)n * 512 + 256 + d0);
        #pragma unroll
        for (int j = 0; j < 8; ++j) xr[j] = bf2f(xv[j]);
    }
    float a[8] = {};
    float den = 0.f;
    int beg = offs[n], end = offs[n + 1];
    for (int i = beg; i < end; i += 2) {
        int idx = i + half;
        bool act = idx < end;
        int s = srcs[act ? idx : (end - 1)];
        bf16x8 xlv = *(const bf16x8*)(C + (size_t)s * 512 + d0);
        float xl[8];
        #pragma unroll
        for (int j = 0; j < 8; ++j) xl[j] = bf2f(xlv[j]);
        float p = 0.f;
        #pragma unroll
        for (int j = 0; j < 8; ++j) p += lrelu(xl[j] + xr[j]) * attv[j];
        p += __shfl_xor(p, 1, 64);
        p += __shfl_xor(p, 2, 64);
        p += __shfl_xor(p, 4, 64);
        float wgt = act ? __expf(p) : 0.f;
        den += wgt;
        #pragma unroll
        for (int j = 0; j < 8; ++j) a[j] += wgt * xl[j];
    }
    den += __shfl_xor(den, 32, 64);
    #pragma unroll
    for (int j = 0; j < 8; ++j) a[j] += __shfl_xor(a[j], 32, 64);
    if (half == 0) {
        float inv = 1.f / (den + 1e-16f);
        bf16x8 o;
        #pragma unroll
        for (int j = 0; j < 8; ++j) o[j] = f2bf(elu1(a[j] * inv + bias[d0 + j]));
        // A'2 layout: [n>>7][kchunk=l5][n&127][8]
        *(bf16x8*)(h1b + (size_t)(n >> 7) * TS2 + (size_t)l5 * 1024 + (size_t)(n & 127) * 8) = o;
    }
}

// ---------------- layer-2 fused (1 head x 256), f32 output ----------------
__global__ __launch_bounds__(256) void fused_aggr2_kernel(
    const int* __restrict__ offs, const int* __restrict__ srcs,
    const short* __restrict__ C, const float* __restrict__ att,
    const float* __restrict__ bias, float* __restrict__ h2)
{
    int wid = (int)((blockIdx.x * 256 + threadIdx.x) >> 6);
    int lane = threadIdx.x & 63;
    if (wid >= N_NODES) return;
    int n = wid;
    int half = lane >> 5;
    int l5 = lane & 31;
    int d0 = l5 * 8;
    float attv[8], xr[8];
    {
        float4 aa = *(const float4*)(att + d0);
        float4 ab = *(const float4*)(att + d0 + 4);
        attv[0]=aa.x; attv[1]=aa.y; attv[2]=aa.z; attv[3]=aa.w;
        attv[4]=ab.x; attv[5]=ab.y; attv[6]=ab.z; attv[7]=ab.w;
        bf16x8 xv = *(const bf16x8*)(C + (size_t)n * 512 + 256 + d0);
        #pragma unroll
        for (int j = 0; j < 8; ++j) xr[j] = bf2f(xv[j]);
    }
    float a[8] = {};
    float den = 0.f;
    int beg = offs[n], end = offs[n + 1];
    for (int i = beg; i < end; i += 2) {
        int idx = i + half;
        bool act = idx < end;
        int s = srcs[act ? idx : (end - 1)];
        bf16x8 xlv = *(const bf16x8*)(C + (size_t)s * 512 + d0);
        float xl[8];
        #pragma unroll
        for (int j = 0; j < 8; ++j) xl[j] = bf2f(xlv[j]);
        float p = 0.f;
        #pragma unroll
        for (int j = 0; j < 8; ++j) p += lrelu(xl[j] + xr[j]) * attv[j];
        p += __shfl_xor(p, 1, 64);
        p += __shfl_xor(p, 2, 64);
        p += __shfl_xor(p, 4, 64);
        p += __shfl_xor(p, 8, 64);
        p += __shfl_xor(p, 16, 64);
        float wgt = act ? __expf(p) : 0.f;
        den += wgt;
        #pragma unroll
        for (int j = 0; j < 8; ++j) a[j] += wgt * xl[j];
    }
    den += __shfl_xor(den, 32, 64);
    #pragma unroll
    for (int j = 0; j < 8; ++j) a[j] += __shfl_xor(a[j], 32, 64);
    if (half == 0) {
        float inv = 1.f / (den + 1e-16f);
        float4 o0, o1;
        o0.x = elu1(a[0] * inv + bias[d0 + 0]);
        o0.y = elu1(a[1] * inv + bias[d0 + 1]);
        o0.z = elu1(a[2] * inv + bias[d0 + 2]);
        o0.w = elu1(a[3] * inv + bias[d0 + 3]);
        o1.x = elu1(a[4] * inv + bias[d0 + 4]);
        o1.y = elu1(a[5] * inv + bias[d0 + 5]);
        o1.z = elu1(a[6] * inv + bias[d0 + 6]);
        o1.w = elu1(a[7] * inv + bias[d0 + 7]);
        *(float4*)(h2 + (size_t)n * 256 + d0) = o0;
        *(float4*)(h2 + (size_t)n * 256 + d0 + 4) = o1;
    }
}

// ---------------- MLP head: one block (128 thr) per batch row ----------------
__global__ __launch_bounds__(128) void head_mlp_kernel(
    const float* __restrict__ h2, const int* __restrict__ sel,
    const float* __restrict__ wt, const float* __restrict__ mut,
    const float* __restrict__ W1, const float* __restrict__ b1,
    const float* __restrict__ W2, const float* __restrict__ b2,
    const float* __restrict__ W3, const float* __restrict__ b3,
    float* __restrict__ out)
{
    __shared__ float comb[296];
    __shared__ float z1[128];
    int b = blockIdx.x;
    int t = threadIdx.x;
    const float* hrow = h2 + (size_t)sel[b] * 256;
    comb[t] = hrow[t];
    comb[128 + t] = hrow[128 + t];
    if (t < 40) comb[256 + t] = (t < 20) ? wt[b * 20 + t] : mut[b * 20 + t - 20];
    __syncthreads();
    float s = b1[t];
    #pragma unroll 8
    for (int i = 0; i < 296; ++i) s += comb[i] * W1[i * 128 + t];
    z1[t] = fmaxf(s, 0.f);
    __syncthreads();
    if (t < 64) {
        float s2 = b2[t];
        #pragma unroll 8
        for (int i = 0; i < 128; ++i) s2 += z1[i] * W2[i * 64 + t];
        float v = fmaxf(s2, 0.f) * W3[t];
        #pragma unroll
        for (int off = 32; off > 0; off >>= 1) v += __shfl_xor(v, off, 64);
        if (t == 0) out[b] = v + b3[0];
    }
}

// ---------------- launch ----------------
extern "C" void kernel_launch(void* const* d_in, const int* in_sizes, int n_in,
                              void* d_out, int out_size, void* d_ws, size_t ws_size,
                              hipStream_t stream) {
    const float* x     = (const float*)d_in[0];
    const int*   ei    = (const int*)  d_in[1];
    const int*   sel   = (const int*)  d_in[2];
    const float* wt    = (const float*)d_in[3];
    const float* mut   = (const float*)d_in[4];
    const float* Wl1   = (const float*)d_in[5];
    const float* bl1   = (const float*)d_in[6];
    const float* Wr1   = (const float*)d_in[7];
    const float* br1   = (const float*)d_in[8];
    const float* att1  = (const float*)d_in[9];
    const float* bias1 = (const float*)d_in[10];
    const float* Wl2   = (const float*)d_in[11];
    const float* bl2   = (const float*)d_in[12];
    const float* Wr2   = (const float*)d_in[13];
    const float* br2   = (const float*)d_in[14];
    const float* att2  = (const float*)d_in[15];
    const float* bias2 = (const float*)d_in[16];
    const float* hW1   = (const float*)d_in[17];
    const float* hb1   = (const float*)d_in[18];
    const float* hW2   = (const float*)d_in[19];
    const float* hb2   = (const float*)d_in[20];
    const float* hW3   = (const float*)d_in[21];
    const float* hb3   = (const float*)d_in[22];
    float* out = (float*)d_out;

    // workspace layout (256B-aligned chunks)
    char* w = (char*)d_ws;
    size_t off = 0;
    auto alloc = [&](size_t bytes) -> void* {
        void* p = w + off;
        off += (bytes + 255) & ~(size_t)255;
        return p;
    };
    short* Abf    = (short*)alloc((size_t)NBM * TS1 * 2);       // x in A'-tiles; reused as C2 (bf16)
    short* Wbf    = (short*)alloc((size_t)4 * TS1 * 2);         // [Wl1|Wr1] in B'-tiles
    short* C1b    = (short*)alloc((size_t)N_NODES * 512 * 2);   // [xl1|xr1] bf16; reused as h2 f32
    int*   counts = (int*)  alloc((size_t)N_NODES * 4);
    int*   cursor = (int*)  alloc((size_t)N_NODES * 4);
    int*   offs   = (int*)  alloc((size_t)(N_NODES + 1) * 4);
    int*   srcs   = (int*)  alloc((size_t)E_TOT * 4);
    short* H1bf   = (short*)alloc((size_t)NBM * TS2 * 2);       // h1 in A'-tiles (GEMM2 A)
    short* W2bf   = (short*)alloc((size_t)4 * TS2 * 2);         // [Wl2|Wr2] in B'-tiles
    short* C2b = Abf;          // [xl2|xr2] bf16 overlays dead x-tiles
    float* h2  = (float*)C1b;  // h2 f32 overlays dead C1b
    (void)in_sizes; (void)n_in; (void)out_size; (void)ws_size;

    hipMemsetAsync(counts, 0, (size_t)N_NODES * 4, stream);

    // pack inputs to tiled bf16
    pack_x_kernel<<<dim3(NBM, 16), 256, 0, stream>>>(x, Abf);
    pack_w_kernel<<<dim3(KP1 / 8, 4), 256, 0, stream>>>(Wl1, Wr1, Wbf, IN_DIM, KP1);
    pack_w_kernel<<<dim3(256 / 8, 4), 256, 0, stream>>>(Wl2, Wr2, W2bf, 256, 256);

    // CSR by dst (shared by both layers)
    edge_count_kernel<<<(E_TOT + 255) / 256, 256, 0, stream>>>(ei, counts);
    scan_kernel<<<1, 1024, 0, stream>>>(counts, offs, cursor);
    edge_scatter_kernel<<<(E_TOT + 255) / 256, 256, 0, stream>>>(ei, cursor, srcs);

    // layer 1
    gemm_bf16_kernel<<<NBM * 4, 256, 0, stream>>>(Abf, Wbf, C1b, bl1, br1, N_NODES, KP1);
    fused_aggr1_kernel<<<(N_NODES + 3) / 4, 256, 0, stream>>>(offs, srcs, C1b, att1, bias1, H1bf);
    // layer 2
    gemm_bf16_kernel<<<NBM * 4, 256, 0, stream>>>(H1bf, W2bf, C2b, bl2, br2, N_NODES, 256);
    fused_aggr2_kernel<<<(N_NODES + 3) / 4, 256, 0, stream>>>(offs, srcs, C2b, att2, bias2, h2);
    // head
    head_mlp_kernel<<<BQ, 128, 0, stream>>>(h2, sel, wt, mut, hW1, hb1, hW2, hb2, hW3, hb3, out);
}

// Round 7
// 604.117 us; speedup vs baseline: 1.0721x; 1.0721x over previous
//
#include <hip/hip_runtime.h>

// ---------------- problem constants ----------------
#define N_NODES 30000
#define N_EDGES 480000
#define E_TOT   510000        // edges + self loops
#define BQ      4096
#define IN_DIM  1281
#define KP1     1344          // 1281 padded to mult of 64 (pack tile) & 32 (gemm)
#define NKG     (KP1/64)      // 21 col-groups in pack_x
#define MP      30080         // 30000 padded to mult of 128
#define NBM     235           // MP/128
#define TS1     (KP1*128)     // A'/B' tile stride (shorts), layer 1
#define TS2     (256*128)     // tile stride, layer 2

typedef __attribute__((ext_vector_type(8))) short bf16x8;
typedef __attribute__((ext_vector_type(4))) float f32x4;

__device__ __forceinline__ short f2bf(float f) {
    unsigned int u = __builtin_bit_cast(unsigned int, f);
    u += 0x7fffu + ((u >> 16) & 1u);       // RNE
    return (short)(u >> 16);
}

__device__ __forceinline__ float bf2f(short s) {
    unsigned int u = ((unsigned int)(unsigned short)s) << 16;
    return __builtin_bit_cast(float, u);
}

__device__ __forceinline__ void async16(void* lds, const void* g) {
    __builtin_amdgcn_global_load_lds(
        (const __attribute__((address_space(1))) void*)g,
        (__attribute__((address_space(3))) void*)lds, 16, 0, 0);
}

__device__ __forceinline__ float elu1(float x) {
    return x > 0.f ? x : __expf(x) - 1.f;
}

__device__ __forceinline__ float lrelu(float x) {
    return x > 0.f ? x : 0.2f * x;
}

// ---------------- pack kernels ----------------
// x (30000x1281 f32) -> A' tile-major: A'[mt][kchunk][m&127][k&7] bf16.
// Block = 128 rows x 64 cols (= 8 kchunks). Phase 1: each wave loads 32
// row-segments as 4 batches of 8 INDEPENDENT scalar dword loads (explicit
// MLP: ~8 loads in flight per wave). Phase 2: 4 passes x 256 threads =
// 1024 contiguous 16-B stores covering this block's 8 kchunks.
// (R6 BUG was here: 8 passes / tc 0..15 wrote into the NEXT kg's chunks
// from out-of-bounds LDS -> garbage A'. Fixed to 4 passes / tc 0..7.)
__global__ __launch_bounds__(256) void pack_x_kernel(const float* __restrict__ x,
                                                     short* __restrict__ A) {
    __shared__ short L[128][72];
    const int mt = blockIdx.x;       // 0..234
    const int kg = blockIdx.y;       // 0..NKG-1
    const int t = threadIdx.x;
    const int wave = t >> 6, lane = t & 63;
    const int m0 = mt * 128;
    const int col = kg * 64 + lane;
    const bool cok = col < IN_DIM;
    const float* xcol = x + col;
    #pragma unroll
    for (int b = 0; b < 4; ++b) {
        float v[8];
        #pragma unroll
        for (int j = 0; j < 8; ++j) {
            int ml = (b * 8 + j) * 4 + wave;
            int m = m0 + ml;
            v[j] = (cok && m < N_NODES) ? xcol[(size_t)m * IN_DIM] : 0.f;
        }
        #pragma unroll
        for (int j = 0; j < 8; ++j) {
            int ml = (b * 8 + j) * 4 + wave;
            L[ml][lane] = f2bf(v[j]);
        }
    }
    __syncthreads();
    short* Atile = A + (size_t)mt * TS1 + (size_t)kg * 8 * 1024;
    #pragma unroll
    for (int pass = 0; pass < 4; ++pass) {
        int u = pass * 256 + t;          // 0..1023
        int tc = u >> 7, ml = u & 127;   // tc 0..7 (this block's 8 kchunks)
        *(bf16x8*)(Atile + (size_t)tc * 1024 + ml * 8) = *(const bf16x8*)&L[ml][tc * 8];
    }
}

// W (K x 256 row-major, Wl|Wr) -> B'[bt][kchunk][n&127][k&7]; k-pad zeroed.
// Block (kc, bt): 8 k-rows x 128 n-cols.
__global__ __launch_bounds__(256) void pack_w_kernel(const float* __restrict__ Wl,
                                                     const float* __restrict__ Wr,
                                                     short* __restrict__ Bt,
                                                     int K, int Kp) {
    __shared__ short L[8][128];
    const int kc = blockIdx.x, bt = blockIdx.y;
    const int t = threadIdx.x;
    const float* W = (bt < 2) ? Wl : Wr;
    const int ncol0 = (bt & 1) * 128;
    #pragma unroll
    for (int pass = 0; pass < 4; ++pass) {
        int u = pass * 256 + t;               // 1024 elems: k_r = u>>7, n_l = u&127
        int k_r = u >> 7, n_l = u & 127;
        int k = kc * 8 + k_r;
        L[k_r][n_l] = (k < K) ? f2bf(W[(size_t)k * 256 + ncol0 + n_l]) : (short)0;
    }
    __syncthreads();
    if (t < 128) {
        bf16x8 v;
        #pragma unroll
        for (int j = 0; j < 8; ++j) v[j] = L[j][t];
        *(bf16x8*)(Bt + (size_t)bt * ((size_t)Kp * 128) + (size_t)kc * 1024 + (size_t)t * 8) = v;
    }
}

// ---------------- bf16 MFMA GEMM, 128x128 tile, tiled layouts ----------------
// C(M x 512 bf16) = A'(tiles) * B'(tiles)^T + bias.
// Staging: per K-iter one contiguous 8-KB slab per matrix. XCD swizzle: 4
// blocks sharing an A-tile get ids == same mod 8 within one 32-id group.
__global__ __launch_bounds__(256) void gemm_bf16_kernel(
    const short* __restrict__ A, const short* __restrict__ B,
    short* __restrict__ C,
    const float* __restrict__ biasLo, const float* __restrict__ biasHi,
    int Mstore, int Kp)
{
    __shared__ short As[4096];   // [4 kc][128 m][8 k]
    __shared__ short Bs[4096];
    const int id = blockIdx.x;
    int bmT, bnT;
    if (id < 928) { int grp = id >> 5, w32 = id & 31; bmT = grp * 8 + (w32 & 7); bnT = w32 >> 3; }
    else          { int r = id - 928;  bmT = 232 + (r >> 2); bnT = r & 3; }
    const int tid  = threadIdx.x;
    const int wave = tid >> 6;
    const int lane = tid & 63;
    const int l15  = lane & 15;
    const int quad = lane >> 4;

    const size_t tstride = (size_t)Kp * 128;
    const short* aPtr = A + (size_t)bmT * tstride + wave * 1024 + lane * 8;
    const short* bPtr = B + (size_t)bnT * tstride + wave * 1024 + lane * 8;
    short* AsW = &As[wave * 1024];
    short* BsW = &Bs[wave * 1024];

    const int wm = (wave & 1) * 64;
    const int wn = (wave >> 1) * 64;

    f32x4 acc[4][4] = {};

    for (int it = 0; it < Kp / 32; ++it) {
        async16(AsW,       aPtr);
        async16(AsW + 512, aPtr + 512);
        async16(BsW,       bPtr);
        async16(BsW + 512, bPtr + 512);
        aPtr += 4096; bPtr += 4096;
        __syncthreads();

        bf16x8 af[4], bfr[4];
        #pragma unroll
        for (int i = 0; i < 4; ++i)
            af[i] = *(const bf16x8*)&As[quad * 1024 + (wm + i * 16 + l15) * 8];
        #pragma unroll
        for (int i = 0; i < 4; ++i)
            bfr[i] = *(const bf16x8*)&Bs[quad * 1024 + (wn + i * 16 + l15) * 8];
        #pragma unroll
        for (int mi = 0; mi < 4; ++mi)
            #pragma unroll
            for (int ni = 0; ni < 4; ++ni)
                acc[mi][ni] = __builtin_amdgcn_mfma_f32_16x16x32_bf16(
                    af[mi], bfr[ni], acc[mi][ni], 0, 0, 0);
        __syncthreads();
    }

    // C/D layout: col = lane&15, row = quad*4 + reg  [measured m89/m91]
    const int bm = bmT * 128, bn = bnT * 128;
    #pragma unroll
    for (int mi = 0; mi < 4; ++mi) {
        int row = bm + wm + mi * 16 + quad * 4;
        #pragma unroll
        for (int ni = 0; ni < 4; ++ni) {
            int col = bn + wn + ni * 16 + l15;
            float bv = (col < 256) ? biasLo[col] : biasHi[col - 256];
            #pragma unroll
            for (int r = 0; r < 4; ++r) {
                int rr = row + r;
                if (rr < Mstore)
                    C[(size_t)rr * 512 + col] = f2bf(acc[mi][ni][r] + bv);
            }
        }
    }
}

// ---------------- CSR build (grouped by dst) ----------------
__global__ __launch_bounds__(256) void edge_count_kernel(const int* __restrict__ ei,
                                                         int* __restrict__ counts) {
    int e = blockIdx.x * 256 + threadIdx.x;
    if (e >= E_TOT) return;
    int dst = (e < N_EDGES) ? ei[N_EDGES + e] : (e - N_EDGES);
    atomicAdd(&counts[dst], 1);
}

// single block, 1024 threads x 32 nodes each; one barrier phase
__global__ __launch_bounds__(1024) void scan_kernel(const int* __restrict__ counts,
                                                    int* __restrict__ offs,
                                                    int* __restrict__ cursor) {
    __shared__ int wsum[16];
    int t = threadIdx.x;
    int lane = t & 63, wv = t >> 6;
    int base = t * 32;
    int local[32];
    int s = 0;
    #pragma unroll
    for (int j = 0; j < 32; ++j) {
        int i = base + j;
        int c = (i < N_NODES) ? counts[i] : 0;
        local[j] = s;
        s += c;
    }
    int incl = s;
    #pragma unroll
    for (int off = 1; off < 64; off <<= 1) {
        int v = __shfl_up(incl, off, 64);
        if (lane >= off) incl += v;
    }
    if (lane == 63) wsum[wv] = incl;
    __syncthreads();
    if (t == 0) {
        int run = 0;
        #pragma unroll
        for (int w2 = 0; w2 < 16; ++w2) { int v = wsum[w2]; wsum[w2] = run; run += v; }
        offs[N_NODES] = run;
    }
    __syncthreads();
    int thrExc = wsum[wv] + incl - s;
    #pragma unroll
    for (int j = 0; j < 32; ++j) {
        int i = base + j;
        if (i < N_NODES) {
            int o = thrExc + local[j];
            offs[i] = o;
            cursor[i] = o;
        }
    }
}

__global__ __launch_bounds__(256) void edge_scatter_kernel(const int* __restrict__ ei,
                                                           int* __restrict__ cursor,
                                                           int* __restrict__ srcs) {
    int e = blockIdx.x * 256 + threadIdx.x;
    if (e >= E_TOT) return;
    int src, dst;
    if (e < N_EDGES) { src = ei[e]; dst = ei[N_EDGES + e]; }
    else { src = e - N_EDGES; dst = src; }
    int pos = atomicAdd(&cursor[dst], 1);
    srcs[pos] = src;
}

// ---------------- layer-1 fused logits+softmax+aggregate ----------------
// one wave per dst node, two edges per iteration (half-waves); lane owns 8 dims.
// Output written directly in A'-tile layout for GEMM2.
__global__ __launch_bounds__(256) void fused_aggr1_kernel(
    const int* __restrict__ offs, const int* __restrict__ srcs,
    const short* __restrict__ C, const float* __restrict__ att,
    const float* __restrict__ bias, short* __restrict__ h1b)
{
    int wid = (int)((blockIdx.x * 256 + threadIdx.x) >> 6);
    int lane = threadIdx.x & 63;
    if (wid >= N_NODES) return;
    int n = wid;
    int half = lane >> 5;
    int l5 = lane & 31;
    int d0 = l5 * 8;
    float attv[8], xr[8];
    {
        float4 aa = *(const float4*)(att + d0);
        float4 ab = *(const float4*)(att + d0 + 4);
        attv[0]=aa.x; attv[1]=aa.y; attv[2]=aa.z; attv[3]=aa.w;
        attv[4]=ab.x; attv[5]=ab.y; attv[6]=ab.z; attv[7]=ab.w;
        bf16x8 xv = *(const bf16x8*)(C + (size_t)n * 512 + 256 + d0);
        #pragma unroll
        for (int j = 0; j < 8; ++j) xr[j] = bf2f(xv[j]);
    }
    float a[8] = {};
    float den = 0.f;
    int beg = offs[n], end = offs[n + 1];
    for (int i = beg; i < end; i += 2) {
        int idx = i + half;
        bool act = idx < end;
        int s = srcs[act ? idx : (end - 1)];
        bf16x8 xlv = *(const bf16x8*)(C + (size_t)s * 512 + d0);
        float xl[8];
        #pragma unroll
        for (int j = 0; j < 8; ++j) xl[j] = bf2f(xlv[j]);
        float p = 0.f;
        #pragma unroll
        for (int j = 0; j < 8; ++j) p += lrelu(xl[j] + xr[j]) * attv[j];
        p += __shfl_xor(p, 1, 64);
        p += __shfl_xor(p, 2, 64);
        p += __shfl_xor(p, 4, 64);
        float wgt = act ? __expf(p) : 0.f;
        den += wgt;
        #pragma unroll
        for (int j = 0; j < 8; ++j) a[j] += wgt * xl[j];
    }
    den += __shfl_xor(den, 32, 64);
    #pragma unroll
    for (int j = 0; j < 8; ++j) a[j] += __shfl_xor(a[j], 32, 64);
    if (half == 0) {
        float inv = 1.f / (den + 1e-16f);
        bf16x8 o;
        #pragma unroll
        for (int j = 0; j < 8; ++j) o[j] = f2bf(elu1(a[j] * inv + bias[d0 + j]));
        // A'2 layout: [n>>7][kchunk=l5][n&127][8]
        *(bf16x8*)(h1b + (size_t)(n >> 7) * TS2 + (size_t)l5 * 1024 + (size_t)(n & 127) * 8) = o;
    }
}

// ---------------- layer-2 fused (1 head x 256), f32 output ----------------
__global__ __launch_bounds__(256) void fused_aggr2_kernel(
    const int* __restrict__ offs, const int* __restrict__ srcs,
    const short* __restrict__ C, const float* __restrict__ att,
    const float* __restrict__ bias, float* __restrict__ h2)
{
    int wid = (int)((blockIdx.x * 256 + threadIdx.x) >> 6);
    int lane = threadIdx.x & 63;
    if (wid >= N_NODES) return;
    int n = wid;
    int half = lane >> 5;
    int l5 = lane & 31;
    int d0 = l5 * 8;
    float attv[8], xr[8];
    {
        float4 aa = *(const float4*)(att + d0);
        float4 ab = *(const float4*)(att + d0 + 4);
        attv[0]=aa.x; attv[1]=aa.y; attv[2]=aa.z; attv[3]=aa.w;
        attv[4]=ab.x; attv[5]=ab.y; attv[6]=ab.z; attv[7]=ab.w;
        bf16x8 xv = *(const bf16x8*)(C + (size_t)n * 512 + 256 + d0);
        #pragma unroll
        for (int j = 0; j < 8; ++j) xr[j] = bf2f(xv[j]);
    }
    float a[8] = {};
    float den = 0.f;
    int beg = offs[n], end = offs[n + 1];
    for (int i = beg; i < end; i += 2) {
        int idx = i + half;
        bool act = idx < end;
        int s = srcs[act ? idx : (end - 1)];
        bf16x8 xlv = *(const bf16x8*)(C + (size_t)s * 512 + d0);
        float xl[8];
        #pragma unroll
        for (int j = 0; j < 8; ++j) xl[j] = bf2f(xlv[j]);
        float p = 0.f;
        #pragma unroll
        for (int j = 0; j < 8; ++j) p += lrelu(xl[j] + xr[j]) * attv[j];
        p += __shfl_xor(p, 1, 64);
        p += __shfl_xor(p, 2, 64);
        p += __shfl_xor(p, 4, 64);
        p += __shfl_xor(p, 8, 64);
        p += __shfl_xor(p, 16, 64);
        float wgt = act ? __expf(p) : 0.f;
        den += wgt;
        #pragma unroll
        for (int j = 0; j < 8; ++j) a[j] += wgt * xl[j];
    }
    den += __shfl_xor(den, 32, 64);
    #pragma unroll
    for (int j = 0; j < 8; ++j) a[j] += __shfl_xor(a[j], 32, 64);
    if (half == 0) {
        float inv = 1.f / (den + 1e-16f);
        float4 o0, o1;
        o0.x = elu1(a[0] * inv + bias[d0 + 0]);
        o0.y = elu1(a[1] * inv + bias[d0 + 1]);
        o0.z = elu1(a[2] * inv + bias[d0 + 2]);
        o0.w = elu1(a[3] * inv + bias[d0 + 3]);
        o1.x = elu1(a[4] * inv + bias[d0 + 4]);
        o1.y = elu1(a[5] * inv + bias[d0 + 5]);
        o1.z = elu1(a[6] * inv + bias[d0 + 6]);
        o1.w = elu1(a[7] * inv + bias[d0 + 7]);
        *(float4*)(h2 + (size_t)n * 256 + d0) = o0;
        *(float4*)(h2 + (size_t)n * 256 + d0 + 4) = o1;
    }
}

// ---------------- MLP head: one block (128 thr) per batch row ----------------
__global__ __launch_bounds__(128) void head_mlp_kernel(
    const float* __restrict__ h2, const int* __restrict__ sel,
    const float* __restrict__ wt, const float* __restrict__ mut,
    const float* __restrict__ W1, const float* __restrict__ b1,
    const float* __restrict__ W2, const float* __restrict__ b2,
    const float* __restrict__ W3, const float* __restrict__ b3,
    float* __restrict__ out)
{
    __shared__ float comb[296];
    __shared__ float z1[128];
    int b = blockIdx.x;
    int t = threadIdx.x;
    const float* hrow = h2 + (size_t)sel[b] * 256;
    comb[t] = hrow[t];
    comb[128 + t] = hrow[128 + t];
    if (t < 40) comb[256 + t] = (t < 20) ? wt[b * 20 + t] : mut[b * 20 + t - 20];
    __syncthreads();
    float s = b1[t];
    #pragma unroll 8
    for (int i = 0; i < 296; ++i) s += comb[i] * W1[i * 128 + t];
    z1[t] = fmaxf(s, 0.f);
    __syncthreads();
    if (t < 64) {
        float s2 = b2[t];
        #pragma unroll 8
        for (int i = 0; i < 128; ++i) s2 += z1[i] * W2[i * 64 + t];
        float v = fmaxf(s2, 0.f) * W3[t];
        #pragma unroll
        for (int off = 32; off > 0; off >>= 1) v += __shfl_xor(v, off, 64);
        if (t == 0) out[b] = v + b3[0];
    }
}

// ---------------- launch ----------------
extern "C" void kernel_launch(void* const* d_in, const int* in_sizes, int n_in,
                              void* d_out, int out_size, void* d_ws, size_t ws_size,
                              hipStream_t stream) {
    const float* x     = (const float*)d_in[0];
    const int*   ei    = (const int*)  d_in[1];
    const int*   sel   = (const int*)  d_in[2];
    const float* wt    = (const float*)d_in[3];
    const float* mut   = (const float*)d_in[4];
    const float* Wl1   = (const float*)d_in[5];
    const float* bl1   = (const float*)d_in[6];
    const float* Wr1   = (const float*)d_in[7];
    const float* br1   = (const float*)d_in[8];
    const float* att1  = (const float*)d_in[9];
    const float* bias1 = (const float*)d_in[10];
    const float* Wl2   = (const float*)d_in[11];
    const float* bl2   = (const float*)d_in[12];
    const float* Wr2   = (const float*)d_in[13];
    const float* br2   = (const float*)d_in[14];
    const float* att2  = (const float*)d_in[15];
    const float* bias2 = (const float*)d_in[16];
    const float* hW1   = (const float*)d_in[17];
    const float* hb1   = (const float*)d_in[18];
    const float* hW2   = (const float*)d_in[19];
    const float* hb2   = (const float*)d_in[20];
    const float* hW3   = (const float*)d_in[21];
    const float* hb3   = (const float*)d_in[22];
    float* out = (float*)d_out;

    // workspace layout (256B-aligned chunks)
    char* w = (char*)d_ws;
    size_t off = 0;
    auto alloc = [&](size_t bytes) -> void* {
        void* p = w + off;
        off += (bytes + 255) & ~(size_t)255;
        return p;
    };
    short* Abf    = (short*)alloc((size_t)NBM * TS1 * 2);       // x in A'-tiles; reused as C2 (bf16)
    short* Wbf    = (short*)alloc((size_t)4 * TS1 * 2);         // [Wl1|Wr1] in B'-tiles
    short* C1b    = (short*)alloc((size_t)N_NODES * 512 * 2);   // [xl1|xr1] bf16; reused as h2 f32
    int*   counts = (int*)  alloc((size_t)N_NODES * 4);
    int*   cursor = (int*)  alloc((size_t)N_NODES * 4);
    int*   offs   = (int*)  alloc((size_t)(N_NODES + 1) * 4);
    int*   srcs   = (int*)  alloc((size_t)E_TOT * 4);
    short* H1bf   = (short*)alloc((size_t)NBM * TS2 * 2);       // h1 in A'-tiles (GEMM2 A)
    short* W2bf   = (short*)alloc((size_t)4 * TS2 * 2);         // [Wl2|Wr2] in B'-tiles
    short* C2b = Abf;          // [xl2|xr2] bf16 overlays dead x-tiles
    float* h2  = (float*)C1b;  // h2 f32 overlays dead C1b
    (void)in_sizes; (void)n_in; (void)out_size; (void)ws_size;

    hipMemsetAsync(counts, 0, (size_t)N_NODES * 4, stream);

    // pack inputs to tiled bf16
    pack_x_kernel<<<dim3(NBM, NKG), 256, 0, stream>>>(x, Abf);
    pack_w_kernel<<<dim3(KP1 / 8, 4), 256, 0, stream>>>(Wl1, Wr1, Wbf, IN_DIM, KP1);
    pack_w_kernel<<<dim3(256 / 8, 4), 256, 0, stream>>>(Wl2, Wr2, W2bf, 256, 256);

    // CSR by dst (shared by both layers)
    edge_count_kernel<<<(E_TOT + 255) / 256, 256, 0, stream>>>(ei, counts);
    scan_kernel<<<1, 1024, 0, stream>>>(counts, offs, cursor);
    edge_scatter_kernel<<<(E_TOT + 255) / 256, 256, 0, stream>>>(ei, cursor, srcs);

    // layer 1
    gemm_bf16_kernel<<<NBM * 4, 256, 0, stream>>>(Abf, Wbf, C1b, bl1, br1, N_NODES, KP1);
    fused_aggr1_kernel<<<(N_NODES + 3) / 4, 256, 0, stream>>>(offs, srcs, C1b, att1, bias1, H1bf);
    // layer 2
    gemm_bf16_kernel<<<NBM * 4, 256, 0, stream>>>(H1bf, W2bf, C2b, bl2, br2, N_NODES, 256);
    fused_aggr2_kernel<<<(N_NODES + 3) / 4, 256, 0, stream>>>(offs, srcs, C2b, att2, bias2, h2);
    // head
    head_mlp_kernel<<<BQ, 128, 0, stream>>>(h2, sel, wt, mut, hW1, hb1, hW2, hb2, hW3, hb3, out);
}